// Round 1
// baseline (893.510 us; speedup 1.0000x reference)
//
#include <hip/hip_runtime.h>

// Conv2.5D disparity-masked conv: N=2, C=32, OUT_C=64, H=W=256, K=3, pad=1.
// out[n,o,l] = sum_p sum_c x_col[n,c,p,l] * (m0[p,l]*w0[o,c,p] + m1*w1 + m2*w2)
// Masks depend only on (n,p,l) via disp->depth math.

#define N_BATCH 2
#define IN_C 32
#define OUT_C 64
#define IMG 256
#define TILE 16          // 16x16 pixel tile per block
#define HALO 18          // TILE + 2
#define HALO2 (HALO*HALO)

// ---------------- weight transpose: wT[p][o][t][c], c contiguous ----------------
__global__ void transpose_w_kernel(const float* __restrict__ w0,
                                   const float* __restrict__ w1,
                                   const float* __restrict__ w2,
                                   float* __restrict__ wT) {
    int idx = blockIdx.x * blockDim.x + threadIdx.x;   // ((p*64 + o)*3 + t)*32 + c
    if (idx >= 9 * OUT_C * 3 * IN_C) return;
    int c = idx & 31;
    int r = idx >> 5;
    int t = r % 3;
    int r2 = r / 3;
    int o = r2 & 63;
    int p = r2 >> 6;
    const float* w = (t == 0) ? w0 : (t == 1) ? w1 : w2;
    wT[idx] = w[(o * IN_C + c) * 9 + p];
}

// ---------------- main kernel ----------------
template <bool USE_WT>
__global__ __launch_bounds__(256) void conv25d_kernel(
    const float* __restrict__ x, const float* __restrict__ disp,
    const float* __restrict__ fx, const float* __restrict__ baseline,
    const float* __restrict__ wT,
    const float* __restrict__ w0, const float* __restrict__ w1,
    const float* __restrict__ w2, float* __restrict__ out) {

    __shared__ float sx[IN_C][HALO2];
    __shared__ float sd[HALO2];

    const int bid  = blockIdx.x;
    const int n    = bid >> 8;            // 256 tiles per image
    const int tile = bid & 255;
    const int tr   = (tile >> 4) * TILE;  // tile row origin
    const int tc   = (tile & 15) * TILE;  // tile col origin
    const int tid  = threadIdx.x;

    // stage disp halo tile
    for (int idx = tid; idx < HALO2; idx += 256) {
        int r = idx / HALO, cc = idx - r * HALO;
        int gr = tr + r - 1, gc = tc + cc - 1;
        float v = 0.f;
        if (gr >= 0 && gr < IMG && gc >= 0 && gc < IMG)
            v = disp[n * (IMG * IMG) + gr * IMG + gc];
        sd[idx] = v;
    }
    // stage x halo tile, all channels
    for (int idx = tid; idx < IN_C * HALO2; idx += 256) {
        int c = idx / HALO2;
        int rem = idx - c * HALO2;
        int r = rem / HALO, cc = rem - r * HALO;
        int gr = tr + r - 1, gc = tc + cc - 1;
        float v = 0.f;
        if (gr >= 0 && gr < IMG && gc >= 0 && gc < IMG)
            v = x[((n * IN_C + c) * IMG + gr) * IMG + gc];
        sx[c][rem] = v;
    }
    __syncthreads();

    const int ty = tid >> 4, tx = tid & 15;
    const float fxv = fx[n];
    const float bf  = baseline[n] * fxv;          // baseline * fx
    const float dc  = sd[(ty + 1) * HALO + (tx + 1)];
    const float cdm = (dc != 0.f) ? dc : 0.f;     // masked center d_col
    const float cd  = bf / fminf(fmaxf(cdm, 0.01f), 256.f);   // center_depth
    const float grng = 16.f * cd / fxv;           // PIXEL_SIZE*DIL*cd/fx
    const float hlf  = grng * 0.5f;               // grid_range / 2

    const int sbase = ty * HALO + tx;
    const size_t obase = (size_t)(n * OUT_C) * (IMG * IMG)
                       + (size_t)((tr + ty) * IMG + (tc + tx));

    for (int og = 0; og < 8; ++og) {              // 8 groups of 8 out-channels
        float acc[8];
        #pragma unroll
        for (int i = 0; i < 8; ++i) acc[i] = 0.f;

        for (int p = 0; p < 9; ++p) {
            const int pi = p / 3;
            const int pj = p - pi * 3;
            const int so = sbase + pi * HALO + pj;

            // masks (recomputed per (og,p) to keep register arrays statically indexed)
            float dval   = sd[so];
            float validp = (dval != 0.f && dc != 0.f) ? 1.f : 0.f;
            float dmv    = dval * validp;
            float depth  = bf / fminf(fmaxf(dmv, 0.01f), 256.f);
            float m0 = (fabsf(depth - (cd + grng)) <= hlf) ? 1.f : 0.f;
            float m1r = (fabsf(depth - cd) <= hlf) ? 1.f : 0.f;
            float m1 = fminf(m1r + 1.f - validp, 1.f);
            float m2 = (fabsf(depth - (cd - grng)) <= hlf) ? 1.f : 0.f;

            float xv[IN_C];
            #pragma unroll
            for (int c = 0; c < IN_C; ++c) xv[c] = sx[c][so];

            if (USE_WT) {
                const float* wp = wT + (p * OUT_C + og * 8) * 96;   // [t][c] chunks of 96
                #pragma unroll
                for (int oi = 0; oi < 8; ++oi) {
                    const float* w = wp + oi * 96;
                    float t0 = 0.f, t1 = 0.f, t2 = 0.f;
                    #pragma unroll
                    for (int c = 0; c < IN_C; ++c) {
                        t0 += w[c]        * xv[c];
                        t1 += w[32 + c]   * xv[c];
                        t2 += w[64 + c]   * xv[c];
                    }
                    acc[oi] += m0 * t0 + m1 * t1 + m2 * t2;
                }
            } else {
                // fallback: original layout w[(o*32+c)*9 + p]
                #pragma unroll
                for (int oi = 0; oi < 8; ++oi) {
                    const int o = og * 8 + oi;
                    const float* b0 = w0 + o * (IN_C * 9) + p;
                    const float* b1 = w1 + o * (IN_C * 9) + p;
                    const float* b2 = w2 + o * (IN_C * 9) + p;
                    float t0 = 0.f, t1 = 0.f, t2 = 0.f;
                    #pragma unroll
                    for (int c = 0; c < IN_C; ++c) {
                        t0 += b0[c * 9] * xv[c];
                        t1 += b1[c * 9] * xv[c];
                        t2 += b2[c * 9] * xv[c];
                    }
                    acc[oi] += m0 * t0 + m1 * t1 + m2 * t2;
                }
            }
        }

        #pragma unroll
        for (int oi = 0; oi < 8; ++oi)
            out[obase + (size_t)(og * 8 + oi) * (IMG * IMG)] = acc[oi];
    }
}

extern "C" void kernel_launch(void* const* d_in, const int* in_sizes, int n_in,
                              void* d_out, int out_size, void* d_ws, size_t ws_size,
                              hipStream_t stream) {
    const float* x        = (const float*)d_in[0];
    const float* disp     = (const float*)d_in[1];
    const float* fx       = (const float*)d_in[2];
    const float* baseline = (const float*)d_in[3];
    const float* w0       = (const float*)d_in[4];
    const float* w1       = (const float*)d_in[5];
    const float* w2       = (const float*)d_in[6];
    float* out            = (float*)d_out;

    const size_t wT_bytes = (size_t)9 * OUT_C * 3 * IN_C * sizeof(float);
    const int n_wT = 9 * OUT_C * 3 * IN_C;
    const int grid = N_BATCH * (IMG / TILE) * (IMG / TILE);   // 512 blocks

    if (ws_size >= wT_bytes) {
        float* wT = (float*)d_ws;
        transpose_w_kernel<<<(n_wT + 255) / 256, 256, 0, stream>>>(w0, w1, w2, wT);
        conv25d_kernel<true><<<grid, 256, 0, stream>>>(x, disp, fx, baseline, wT,
                                                       w0, w1, w2, out);
    } else {
        conv25d_kernel<false><<<grid, 256, 0, stream>>>(x, disp, fx, baseline, nullptr,
                                                        w0, w1, w2, out);
    }
}

// Round 2
// 140.369 us; speedup vs baseline: 6.3654x; 6.3654x over previous
//
#include <hip/hip_runtime.h>
#include <hip/hip_bf16.h>

// Conv2.5D disparity-masked conv as implicit GEMM on bf16 MFMA.
// out[n,o,l] = sum_{p,t,c} W_t[o,c,p] * x_col[c,p,l] * m_t[p,l],  m_t in {0,1}
// GEMM: D[o,pix] = sum_k W[o,k] * Xm[k,pix],  K = 9*3*32 = 864 (54 chunks of 16)
// MFMA v_mfma_f32_32x32x16_bf16: D 32x32, A 32(o)x16(k), B 16(k)x32(pix).

#define IN_C 32
#define OUT_C 64
#define IMG 256

typedef __bf16 bf16x8 __attribute__((ext_vector_type(8)));
typedef float f32x16 __attribute__((ext_vector_type(16)));

union B128 { uint4 i4; bf16x8 v; };

// ---- prep: weights into A-fragment order ----------------------------------
// wA[q][ot][lane][j] bf16, q = p*6 + t*2 + chalf (54), ot in {0,1}.
// A element for chunk q: A[m = ot*32 + (lane&31)][k_in = (lane>>5)*8 + j],
// c = chalf*16 + k_in, p = q/6, t = (q%6)>>1.
__global__ void build_wA(const float* __restrict__ w0,
                         const float* __restrict__ w1,
                         const float* __restrict__ w2,
                         __hip_bfloat16* __restrict__ wA) {
    int tid = blockIdx.x * 256 + threadIdx.x;      // q*128 + ot*64 + lane
    if (tid >= 54 * 128) return;
    int lane  = tid & 63;
    int ot    = (tid >> 6) & 1;
    int q     = tid >> 7;
    int p     = q / 6;
    int rm    = q - p * 6;
    int t     = rm >> 1;
    int chalf = rm & 1;
    int o     = ot * 32 + (lane & 31);
    int cbase = chalf * 16 + (lane >> 5) * 8;
    const float* w = (t == 0) ? w0 : (t == 1) ? w1 : w2;
    __hip_bfloat16* dst = wA + (size_t)tid * 8;
    #pragma unroll
    for (int j = 0; j < 8; ++j) {
        float v = w[(o * IN_C + cbase + j) * 9 + p];
        dst[j] = __float2bfloat16(v);
    }
}

// ---- main kernel ----------------------------------------------------------
__global__ __launch_bounds__(256, 4) void conv25d_mfma(
    const float* __restrict__ x, const float* __restrict__ disp,
    const float* __restrict__ fx, const float* __restrict__ baseline,
    const uint4* __restrict__ wA, float* __restrict__ out) {

    // LDS: masks 9*3*128 u32 = 13824 B; Xm 128 pix * 52 u32 (104 bf16) = 26624 B
    __shared__ unsigned smem_masks[9 * 3 * 128];
    __shared__ __align__(16) unsigned smem_xm[128 * 52];
    // center-value arrays alias the Xm region (dead once the p-loop starts)
    float* scd0 = (float*)smem_xm;        // raw center disp
    float* scd  = scd0 + 128;             // center depth
    float* sgr  = scd  + 128;             // grid_range
    float* shf  = sgr  + 128;             // half

    const int tid = threadIdx.x;
    const int bid = blockIdx.x;
    const int n       = bid >> 9;
    const int rem     = bid & 511;
    const int row     = rem >> 1;
    const int colbase = (rem & 1) << 7;   // 0 or 128

    const float fxv = fx[n];
    const float bf  = baseline[n] * fxv;

    // phase A: per-pixel center values
    if (tid < 128) {
        float dc = disp[(n * IMG + row) * IMG + colbase + tid];
        float cd = bf / fminf(fmaxf(dc, 0.01f), 256.f);   // d_center*valid == dc
        float g  = 16.f * cd / fxv;
        scd0[tid] = dc; scd[tid] = cd; sgr[tid] = g; shf[tid] = g * 0.5f;
    }
    __syncthreads();

    // phase B: masks as 0 / 0xFFFFFFFF words
    for (int idx = tid; idx < 9 * 128; idx += 256) {
        int p = idx >> 7, pix = idx & 127;
        int pi = p / 3, pj = p - pi * 3;
        int r = row + pi - 1, cc = colbase + pix + pj - 1;
        float dval = 0.f;
        if (r >= 0 && r < IMG && cc >= 0 && cc < IMG)
            dval = disp[(n * IMG + r) * IMG + cc];
        float dc = scd0[pix];
        bool validp = (dval != 0.f) && (dc != 0.f);
        float dmv   = validp ? dval : 0.f;
        float depth = bf / fminf(fmaxf(dmv, 0.01f), 256.f);
        float cd = scd[pix], g = sgr[pix], h = shf[pix];
        bool m0 = fabsf(depth - (cd + g)) <= h;
        bool m1 = (fabsf(depth - cd) <= h) || (!validp);  // min(m1r+1-valid,1)
        bool m2 = fabsf(depth - (cd - g)) <= h;
        smem_masks[(p * 3 + 0) * 128 + pix] = m0 ? 0xFFFFFFFFu : 0u;
        smem_masks[(p * 3 + 1) * 128 + pix] = m1 ? 0xFFFFFFFFu : 0u;
        smem_masks[(p * 3 + 2) * 128 + pix] = m2 ? 0xFFFFFFFFu : 0u;
    }
    // (barrier at top of p-loop orders phase B vs first Xm build)

    const int lane = tid & 63;
    const int wv   = tid >> 6;      // wave id = pixel-tile (32 pix)
    const int l31  = lane & 31;
    const int half = lane >> 5;
    const int bpix = tid & 63;      // build: pixel id (co-octet = wv)

    f32x16 acc0, acc1;
    #pragma unroll
    for (int rr = 0; rr < 16; ++rr) { acc0[rr] = 0.f; acc1[rr] = 0.f; }

    const uint4* bsrc = reinterpret_cast<const uint4*>(smem_xm)
                      + (wv * 32 + l31) * 13 + half;

    #pragma unroll 1
    for (int p = 0; p < 9; ++p) {
        __syncthreads();            // prev MFMA reads done; (p==0) masks ready
        // ---- build Xm_p: Xm[pix][t*32+c] = bf16(x[c, r, cc]) & mask[t,pix]
        const int pi = p / 3;
        const int pj = p - pi * 3;
        const int r  = row + pi - 1;
        const bool rowok = (r >= 0) && (r < IMG);
        const float* xb = x + ((size_t)(n * IN_C + wv * 8) * IMG
                               + (rowok ? r : 0)) * IMG;
        #pragma unroll
        for (int i = 0; i < 2; ++i) {
            int pix = bpix + 64 * i;
            int cc  = colbase + pix + pj - 1;
            bool ok = rowok && (cc >= 0) && (cc < IMG);
            float xv[8];
            #pragma unroll
            for (int cj = 0; cj < 8; ++cj)
                xv[cj] = ok ? xb[(size_t)cj * IMG * IMG + cc] : 0.f;
            unsigned pk[4];
            #pragma unroll
            for (int j = 0; j < 4; ++j) {
                __hip_bfloat162 h2 =
                    __float22bfloat162_rn(make_float2(xv[2 * j], xv[2 * j + 1]));
                pk[j] = *reinterpret_cast<unsigned*>(&h2);
            }
            unsigned* dst = smem_xm + pix * 52 + wv * 4;
            #pragma unroll
            for (int t = 0; t < 3; ++t) {
                unsigned m = smem_masks[(p * 3 + t) * 128 + pix];
                uint4 v = make_uint4(pk[0] & m, pk[1] & m, pk[2] & m, pk[3] & m);
                *reinterpret_cast<uint4*>(dst + t * 16) = v;
            }
        }
        __syncthreads();
        // ---- MFMA: 6 k-chunks of 16, 2 o-tiles
        const uint4* asrc = wA + (size_t)(p * 6) * 128 + lane;
        #pragma unroll
        for (int kq = 0; kq < 6; ++kq) {
            B128 b, a0, a1;
            b.i4  = bsrc[kq * 2];
            a0.i4 = asrc[kq * 128];
            a1.i4 = asrc[kq * 128 + 64];
            acc0 = __builtin_amdgcn_mfma_f32_32x32x16_bf16(a0.v, b.v, acc0, 0, 0, 0);
            acc1 = __builtin_amdgcn_mfma_f32_32x32x16_bf16(a1.v, b.v, acc1, 0, 0, 0);
        }
    }

    // ---- epilogue: D[o_local = (reg&3)+8*(reg>>2)+4*half][pix = l31]
    float* obase = out + ((size_t)(n * OUT_C) * IMG + row) * IMG
                 + colbase + wv * 32 + l31;
    #pragma unroll
    for (int reg = 0; reg < 16; ++reg) {
        int ol = (reg & 3) + 8 * (reg >> 2) + 4 * half;
        obase[(size_t)ol * IMG * IMG]        = acc0[reg];
        obase[(size_t)(ol + 32) * IMG * IMG] = acc1[reg];
    }
}

extern "C" void kernel_launch(void* const* d_in, const int* in_sizes, int n_in,
                              void* d_out, int out_size, void* d_ws, size_t ws_size,
                              hipStream_t stream) {
    const float* x        = (const float*)d_in[0];
    const float* disp     = (const float*)d_in[1];
    const float* fx       = (const float*)d_in[2];
    const float* baseline = (const float*)d_in[3];
    const float* w0       = (const float*)d_in[4];
    const float* w1       = (const float*)d_in[5];
    const float* w2       = (const float*)d_in[6];
    float* out            = (float*)d_out;

    __hip_bfloat16* wA = (__hip_bfloat16*)d_ws;   // 54*128*8*2 = 110592 B

    build_wA<<<27, 256, 0, stream>>>(w0, w1, w2, wA);
    conv25d_mfma<<<1024, 256, 0, stream>>>(x, disp, fx, baseline,
                                           (const uint4*)wA, out);
}

// Round 3
// 110.157 us; speedup vs baseline: 8.1112x; 1.2743x over previous
//
#include <hip/hip_runtime.h>
#include <hip/hip_bf16.h>

// Conv2.5D disparity-masked conv as implicit GEMM on bf16 MFMA, v3.
// D[o,l] = sum_{p,t,c} W_t[o,c,p] * x[c, l shifted by p] * m_t[p,l]
// Masks m_t[p,l] depend only on the OUTPUT pixel l -> 27 fixed bits per lane.
// B-fragments are built in registers: raw bf16 x from LDS planes & broadcast mask.
// One __syncthreads total; no per-p restaging.

#define IN_C 32
#define OUT_C 64
#define IMG 256

typedef __bf16 bf16x8 __attribute__((ext_vector_type(8)));
typedef float f32x16 __attribute__((ext_vector_type(16)));
union B128 { uint4 i4; bf16x8 v; };

// ---- prep 1: weights into A-fragment order (proven in round 2) -------------
// wA[q][ot][lane] (uint4 each), q = p*6 + t*2 + chalf.
// A[m = ot*32 + (lane&31)][k_in = (lane>>5)*8 + j], c = chalf*16 + k_in.
__global__ void build_wA(const float* __restrict__ w0,
                         const float* __restrict__ w1,
                         const float* __restrict__ w2,
                         __hip_bfloat16* __restrict__ wA) {
    int tid = blockIdx.x * 256 + threadIdx.x;      // q*128 + ot*64 + lane
    if (tid >= 54 * 128) return;
    int lane  = tid & 63;
    int ot    = (tid >> 6) & 1;
    int q     = tid >> 7;
    int p     = q / 6;
    int rm    = q - p * 6;
    int t     = rm >> 1;
    int chalf = rm & 1;
    int o     = ot * 32 + (lane & 31);
    int cbase = chalf * 16 + (lane >> 5) * 8;
    const float* w = (t == 0) ? w0 : (t == 1) ? w1 : w2;
    __hip_bfloat16* dst = wA + (size_t)tid * 8;
    #pragma unroll
    for (int j = 0; j < 8; ++j) {
        float v = w[(o * IN_C + cbase + j) * 9 + p];
        dst[j] = __float2bfloat16(v);
    }
}

// ---- prep 2: x fp32 [c][pix] -> bf16 pixel-major xb[n][pix][c] (64 B/pixel) -
__global__ __launch_bounds__(256) void build_xb(const float* __restrict__ x,
                                                uint4* __restrict__ xb) {
    int pixg = blockIdx.x * 256 + threadIdx.x;     // n*65536 + pix
    int n    = pixg >> 16;
    int pix  = pixg & 65535;
    const float* src = x + ((size_t)n * IN_C) * 65536 + pix;
    unsigned w[16];
    #pragma unroll
    for (int j = 0; j < 16; ++j) {
        float a = src[(size_t)(2 * j) * 65536];
        float b = src[(size_t)(2 * j + 1) * 65536];
        __hip_bfloat162 h2 = __float22bfloat162_rn(make_float2(a, b));
        w[j] = *reinterpret_cast<unsigned*>(&h2);
    }
    uint4* dst = xb + (size_t)pixg * 4;
    dst[0] = make_uint4(w[0],  w[1],  w[2],  w[3]);
    dst[1] = make_uint4(w[4],  w[5],  w[6],  w[7]);
    dst[2] = make_uint4(w[8],  w[9],  w[10], w[11]);
    dst[3] = make_uint4(w[12], w[13], w[14], w[15]);
}

// ---- main kernel -----------------------------------------------------------
// Block = one output row (256 pixels), 4 waves x 64 pixels, 2 n x 256 rows = 512 blocks.
__global__ __launch_bounds__(256, 2) void conv25d_mfma3(
    const uint4* __restrict__ xb, const float* __restrict__ disp,
    const float* __restrict__ fx, const float* __restrict__ baseline,
    const uint4* __restrict__ wA, float* __restrict__ out) {

    // x halo strip as 4 k-slot planes: sx[(s*3 + r')*258 + cc2], 16 B entries.
    // plane s holds channels [s*8, s*8+8) of pixel (row+r'-1, cc2-1). 49.5 KB.
    __shared__ __align__(16) uint4 sx[12 * 258];
    __shared__ float sdisp[3 * 258];               // disp halo strip, 3.1 KB

    const int tid = threadIdx.x;
    const int bid = blockIdx.x;
    const int n   = bid >> 8;
    const int row = bid & 255;

    // stage disp halo
    for (int idx = tid; idx < 3 * 258; idx += 256) {
        int r = idx / 258, cc2 = idx - r * 258;
        int gr = row + r - 1, gc = cc2 - 1;
        float v = 0.f;
        if (gr >= 0 && gr < IMG && gc >= 0 && gc < IMG)
            v = disp[(n * IMG + gr) * IMG + gc];
        sdisp[idx] = v;
    }
    // stage x halo strip into planes
    for (int idx = tid; idx < 3 * 258; idx += 256) {
        int r = idx / 258, cc2 = idx - r * 258;
        int gr = row + r - 1, gc = cc2 - 1;
        uint4 v[4];
        #pragma unroll
        for (int s = 0; s < 4; ++s) v[s] = make_uint4(0u, 0u, 0u, 0u);
        if (gr >= 0 && gr < IMG && gc >= 0 && gc < IMG) {
            const uint4* src = xb + ((size_t)(n * IMG + gr) * IMG + gc) * 4;
            #pragma unroll
            for (int s = 0; s < 4; ++s) v[s] = src[s];
        }
        #pragma unroll
        for (int s = 0; s < 4; ++s) sx[(s * 3 + r) * 258 + cc2] = v[s];
    }
    __syncthreads();   // the only barrier

    const int lane = tid & 63;
    const int wv   = tid >> 6;        // wave owns cols [wv*64, wv*64+64)
    const int l31  = lane & 31;
    const int half = lane >> 5;
    const float fxv = fx[n];
    const float bfx = baseline[n] * fxv;

    // 27 mask bits per owned pixel (fixed across the whole K-loop)
    unsigned mbits[2];
    #pragma unroll
    for (int pt = 0; pt < 2; ++pt) {
        int l = wv * 64 + pt * 32 + l31;
        float dc = sdisp[258 + l + 1];
        float cd = bfx / fminf(fmaxf(dc, 0.01f), 256.f);
        float g  = 16.f * cd / fxv;
        float h  = g * 0.5f;
        unsigned bits = 0u;
        #pragma unroll
        for (int p = 0; p < 9; ++p) {
            int pi = p / 3, pj = p - pi * 3;
            float dval = sdisp[pi * 258 + l + pj];
            bool validp = (dval != 0.f) && (dc != 0.f);
            float dmv   = validp ? dval : 0.f;
            float depth = bfx / fminf(fmaxf(dmv, 0.01f), 256.f);
            bool m0 = fabsf(depth - (cd + g)) <= h;
            bool m1 = (fabsf(depth - cd) <= h) || (!validp);
            bool m2 = fabsf(depth - (cd - g)) <= h;
            bits |= ((m0 ? 1u : 0u) << (3 * p))
                  | ((m1 ? 1u : 0u) << (3 * p + 1))
                  | ((m2 ? 1u : 0u) << (3 * p + 2));
        }
        mbits[pt] = bits;
    }

    f32x16 acc[2][2];   // [ot][pt]
    #pragma unroll
    for (int a = 0; a < 2; ++a)
        #pragma unroll
        for (int b = 0; b < 2; ++b)
            #pragma unroll
            for (int r = 0; r < 16; ++r) acc[a][b][r] = 0.f;

    const int cbase0 = wv * 64 + l31;

    #pragma unroll
    for (int p = 0; p < 9; ++p) {
        const int pi = p / 3, pj = p - pi * 3;
        // raw bf16 x fragments from LDS planes (lane-contiguous 16B reads)
        B128 xr[2][2];   // [pt][chalf]; plane s = chalf*2 + half
        #pragma unroll
        for (int pt = 0; pt < 2; ++pt) {
            int cc2 = cbase0 + pt * 32 + pj;
            #pragma unroll
            for (int ch = 0; ch < 2; ++ch) {
                int s = ch * 2 + half;
                xr[pt][ch].i4 = sx[(s * 3 + pi) * 258 + cc2];
            }
        }
        #pragma unroll
        for (int t = 0; t < 3; ++t) {
            unsigned m0 = 0u - ((mbits[0] >> (3 * p + t)) & 1u);
            unsigned m1 = 0u - ((mbits[1] >> (3 * p + t)) & 1u);
            #pragma unroll
            for (int ch = 0; ch < 2; ++ch) {
                B128 b0, b1, a0, a1;
                b0.i4 = make_uint4(xr[0][ch].i4.x & m0, xr[0][ch].i4.y & m0,
                                   xr[0][ch].i4.z & m0, xr[0][ch].i4.w & m0);
                b1.i4 = make_uint4(xr[1][ch].i4.x & m1, xr[1][ch].i4.y & m1,
                                   xr[1][ch].i4.z & m1, xr[1][ch].i4.w & m1);
                int q = p * 6 + t * 2 + ch;
                a0.i4 = wA[q * 128 + lane];
                a1.i4 = wA[q * 128 + 64 + lane];
                acc[0][0] = __builtin_amdgcn_mfma_f32_32x32x16_bf16(a0.v, b0.v, acc[0][0], 0, 0, 0);
                acc[1][0] = __builtin_amdgcn_mfma_f32_32x32x16_bf16(a1.v, b0.v, acc[1][0], 0, 0, 0);
                acc[0][1] = __builtin_amdgcn_mfma_f32_32x32x16_bf16(a0.v, b1.v, acc[0][1], 0, 0, 0);
                acc[1][1] = __builtin_amdgcn_mfma_f32_32x32x16_bf16(a1.v, b1.v, acc[1][1], 0, 0, 0);
            }
        }
    }

    // epilogue: D[o_local = (reg&3)+8*(reg>>2)+4*half][col = l31] (round-2 proven)
    float* ob = out + ((size_t)(n * OUT_C) * IMG + row) * IMG + wv * 64 + l31;
    #pragma unroll
    for (int ot = 0; ot < 2; ++ot)
        #pragma unroll
        for (int pt = 0; pt < 2; ++pt)
            #pragma unroll
            for (int reg = 0; reg < 16; ++reg) {
                int ol = (reg & 3) + 8 * (reg >> 2) + 4 * half + ot * 32;
                ob[(size_t)ol * IMG * IMG + pt * 32] = acc[ot][pt][reg];
            }
}

extern "C" void kernel_launch(void* const* d_in, const int* in_sizes, int n_in,
                              void* d_out, int out_size, void* d_ws, size_t ws_size,
                              hipStream_t stream) {
    const float* x        = (const float*)d_in[0];
    const float* disp     = (const float*)d_in[1];
    const float* fx       = (const float*)d_in[2];
    const float* baseline = (const float*)d_in[3];
    const float* w0       = (const float*)d_in[4];
    const float* w1       = (const float*)d_in[5];
    const float* w2       = (const float*)d_in[6];
    float* out            = (float*)d_out;

    // ws layout: wA (110592 B, 16B-aligned) | xb (2*65536*64 B = 8388608 B)
    __hip_bfloat16* wA = (__hip_bfloat16*)d_ws;
    uint4* xbuf = (uint4*)((char*)d_ws + 131072);

    build_wA<<<27, 256, 0, stream>>>(w0, w1, w2, wA);
    build_xb<<<512, 256, 0, stream>>>(x, xbuf);
    conv25d_mfma3<<<512, 256, 0, stream>>>(xbuf, disp, fx, baseline,
                                           (const uint4*)wA, out);
}

// Round 4
// 106.834 us; speedup vs baseline: 8.3635x; 1.0311x over previous
//
#include <hip/hip_runtime.h>
#include <hip/hip_bf16.h>

// Conv2.5D disparity-masked conv as implicit GEMM on bf16 MFMA, v4.
// D[o,l] = sum_{p,t,c} W_t[o,c,p] * x[c, l shifted by p] * m_t[p,l]
// v4: wave = 32 outs x 128 pixels (A-traffic halved vs v3); x fp32->bf16
// conversion fused into the halo staging (build_xb kernel removed).

#define IN_C 32
#define OUT_C 64
#define IMG 256

typedef __bf16 bf16x8 __attribute__((ext_vector_type(8)));
typedef float f32x16 __attribute__((ext_vector_type(16)));
union B128 { uint4 i4; bf16x8 v; };

// ---- prep: weights into A-fragment order (proven in rounds 2-3) ------------
// wA[q][ot][lane] (uint4 each), q = p*6 + t*2 + chalf.
// A[m = ot*32 + (lane&31)][k_in = (lane>>5)*8 + j], c = chalf*16 + k_in.
__global__ void build_wA(const float* __restrict__ w0,
                         const float* __restrict__ w1,
                         const float* __restrict__ w2,
                         __hip_bfloat16* __restrict__ wA) {
    int tid = blockIdx.x * 256 + threadIdx.x;      // q*128 + ot*64 + lane
    if (tid >= 54 * 128) return;
    int lane  = tid & 63;
    int ot    = (tid >> 6) & 1;
    int q     = tid >> 7;
    int p     = q / 6;
    int rm    = q - p * 6;
    int t     = rm >> 1;
    int chalf = rm & 1;
    int o     = ot * 32 + (lane & 31);
    int cbase = chalf * 16 + (lane >> 5) * 8;
    const float* w = (t == 0) ? w0 : (t == 1) ? w1 : w2;
    __hip_bfloat16* dst = wA + (size_t)tid * 8;
    #pragma unroll
    for (int j = 0; j < 8; ++j) {
        float v = w[(o * IN_C + cbase + j) * 9 + p];
        dst[j] = __float2bfloat16(v);
    }
}

// ---- main kernel -----------------------------------------------------------
// Block = one output row (256 px), 4 waves. Wave w: ot = w&1 (32 outs),
// ph = w>>1 (128 px as 4 groups of 32). 512 blocks = 2 blocks/CU.
__global__ __launch_bounds__(256, 2) void conv25d_mfma4(
    const float* __restrict__ x, const float* __restrict__ disp,
    const float* __restrict__ fx, const float* __restrict__ baseline,
    const uint4* __restrict__ wA, float* __restrict__ out) {

    // x halo strip as 4 k-slot planes: sx[(s*3 + r')*258 + cc2], 16 B entries.
    // plane s holds channels [s*8, s*8+8) of pixel (row+r'-1, cc2-1). 49.5 KB.
    __shared__ __align__(16) uint4 sx[12 * 258];
    __shared__ float sdisp[3 * 258];               // disp halo strip, 3.1 KB

    const int tid = threadIdx.x;
    const int bid = blockIdx.x;
    const int n   = bid >> 8;
    const int row = bid & 255;

    // stage disp halo
    for (int idx = tid; idx < 3 * 258; idx += 256) {
        int r = idx / 258, cc2 = idx - r * 258;
        int gr = row + r - 1, gc = cc2 - 1;
        float v = 0.f;
        if (gr >= 0 && gr < IMG && gc >= 0 && gc < IMG)
            v = disp[(n * IMG + gr) * IMG + gc];
        sdisp[idx] = v;
    }
    // stage x halo strip: fp32 global -> bf16 LDS planes (conversion fused)
    for (int idx = tid; idx < 3 * 258; idx += 256) {
        int r = idx / 258, cc2 = idx - r * 258;
        int gr = row + r - 1, gc = cc2 - 1;
        bool ok = (gr >= 0) && (gr < IMG) && (gc >= 0) && (gc < IMG);
        unsigned w[16];
        #pragma unroll
        for (int j = 0; j < 16; ++j) w[j] = 0u;
        if (ok) {
            const float* src = x + ((size_t)(n * IN_C) * IMG + gr) * IMG + gc;
            #pragma unroll
            for (int j = 0; j < 16; ++j) {
                float a = src[(size_t)(2 * j) * (IMG * IMG)];
                float b = src[(size_t)(2 * j + 1) * (IMG * IMG)];
                __hip_bfloat162 h2 = __float22bfloat162_rn(make_float2(a, b));
                w[j] = *reinterpret_cast<unsigned*>(&h2);
            }
        }
        sx[(0 * 3 + r) * 258 + cc2] = make_uint4(w[0],  w[1],  w[2],  w[3]);
        sx[(1 * 3 + r) * 258 + cc2] = make_uint4(w[4],  w[5],  w[6],  w[7]);
        sx[(2 * 3 + r) * 258 + cc2] = make_uint4(w[8],  w[9],  w[10], w[11]);
        sx[(3 * 3 + r) * 258 + cc2] = make_uint4(w[12], w[13], w[14], w[15]);
    }
    __syncthreads();   // the only barrier

    const int lane = tid & 63;
    const int wv   = tid >> 6;
    const int ot   = wv & 1;          // out-half: outs [ot*32, ot*32+32)
    const int ph   = wv >> 1;         // pixel-half: cols [ph*128, ph*128+128)
    const int l31  = lane & 31;
    const int half = lane >> 5;
    const float fxv = fx[n];
    const float bfx = baseline[n] * fxv;

    // 27 mask bits per owned pixel (4 pixel-groups of 32)
    unsigned mbits[4];
    #pragma unroll
    for (int pg = 0; pg < 4; ++pg) {
        int l = ph * 128 + pg * 32 + l31;
        float dc = sdisp[258 + l + 1];
        float cd = bfx / fminf(fmaxf(dc, 0.01f), 256.f);
        float g  = 16.f * cd / fxv;
        float h  = g * 0.5f;
        unsigned bits = 0u;
        #pragma unroll
        for (int p = 0; p < 9; ++p) {
            int pi = p / 3, pj = p - pi * 3;
            float dval = sdisp[pi * 258 + l + pj];
            bool validp = (dval != 0.f) && (dc != 0.f);
            float dmv   = validp ? dval : 0.f;
            float depth = bfx / fminf(fmaxf(dmv, 0.01f), 256.f);
            bool m0 = fabsf(depth - (cd + g)) <= h;
            bool m1 = (fabsf(depth - cd) <= h) || (!validp);
            bool m2 = fabsf(depth - (cd - g)) <= h;
            bits |= ((m0 ? 1u : 0u) << (3 * p))
                  | ((m1 ? 1u : 0u) << (3 * p + 1))
                  | ((m2 ? 1u : 0u) << (3 * p + 2));
        }
        mbits[pg] = bits;
    }

    f32x16 acc[4];     // [pg]
    #pragma unroll
    for (int pg = 0; pg < 4; ++pg)
        #pragma unroll
        for (int r = 0; r < 16; ++r) acc[pg][r] = 0.f;

    const int cbase0 = ph * 128 + l31;

    #pragma unroll
    for (int p = 0; p < 9; ++p) {
        const int pi = p / 3, pj = p - pi * 3;
        // raw bf16 x fragments (lane-contiguous b128 LDS reads)
        B128 xr[4][2];   // [pg][chalf]; plane s = chalf*2 + half
        #pragma unroll
        for (int pg = 0; pg < 4; ++pg) {
            int cc2 = cbase0 + pg * 32 + pj;
            #pragma unroll
            for (int ch = 0; ch < 2; ++ch)
                xr[pg][ch].i4 = sx[((ch * 2 + half) * 3 + pi) * 258 + cc2];
        }
        #pragma unroll
        for (int t = 0; t < 3; ++t) {
            B128 a0, a1;   // A-frags for chalf 0/1, this wave's ot only
            a0.i4 = wA[(p * 6 + t * 2 + 0) * 128 + ot * 64 + lane];
            a1.i4 = wA[(p * 6 + t * 2 + 1) * 128 + ot * 64 + lane];
            unsigned m[4];
            #pragma unroll
            for (int pg = 0; pg < 4; ++pg)
                m[pg] = 0u - ((mbits[pg] >> (3 * p + t)) & 1u);
            // ch-outer / pg-inner: same-acc MFMAs separated by 3 others
            #pragma unroll
            for (int pg = 0; pg < 4; ++pg) {
                B128 b;
                b.i4 = make_uint4(xr[pg][0].i4.x & m[pg], xr[pg][0].i4.y & m[pg],
                                  xr[pg][0].i4.z & m[pg], xr[pg][0].i4.w & m[pg]);
                acc[pg] = __builtin_amdgcn_mfma_f32_32x32x16_bf16(a0.v, b.v, acc[pg], 0, 0, 0);
            }
            #pragma unroll
            for (int pg = 0; pg < 4; ++pg) {
                B128 b;
                b.i4 = make_uint4(xr[pg][1].i4.x & m[pg], xr[pg][1].i4.y & m[pg],
                                  xr[pg][1].i4.z & m[pg], xr[pg][1].i4.w & m[pg]);
                acc[pg] = __builtin_amdgcn_mfma_f32_32x32x16_bf16(a1.v, b.v, acc[pg], 0, 0, 0);
            }
        }
    }

    // epilogue: D[o_local = (reg&3)+8*(reg>>2)+4*half][col = l31] (proven)
    float* ob = out + (size_t)(n * OUT_C) * (IMG * IMG)
              + (size_t)row * IMG + ph * 128 + l31;
    #pragma unroll
    for (int pg = 0; pg < 4; ++pg)
        #pragma unroll
        for (int reg = 0; reg < 16; ++reg) {
            int ol = (reg & 3) + 8 * (reg >> 2) + 4 * half + ot * 32;
            ob[(size_t)ol * (IMG * IMG) + pg * 32] = acc[pg][reg];
        }
}

extern "C" void kernel_launch(void* const* d_in, const int* in_sizes, int n_in,
                              void* d_out, int out_size, void* d_ws, size_t ws_size,
                              hipStream_t stream) {
    const float* x        = (const float*)d_in[0];
    const float* disp     = (const float*)d_in[1];
    const float* fx       = (const float*)d_in[2];
    const float* baseline = (const float*)d_in[3];
    const float* w0       = (const float*)d_in[4];
    const float* w1       = (const float*)d_in[5];
    const float* w2       = (const float*)d_in[6];
    float* out            = (float*)d_out;

    __hip_bfloat16* wA = (__hip_bfloat16*)d_ws;   // 54*128*16 = 110592 B

    build_wA<<<27, 256, 0, stream>>>(w0, w1, w2, wA);
    conv25d_mfma4<<<512, 256, 0, stream>>>(x, disp, fx, baseline,
                                           (const uint4*)wA, out);
}

// Round 5
// 102.686 us; speedup vs baseline: 8.7014x; 1.0404x over previous
//
#include <hip/hip_runtime.h>
#include <hip/hip_bf16.h>

// Conv2.5D disparity-masked conv as implicit GEMM on bf16 MFMA, v5.
// D[o,l] = sum_{p,t,c} W_t[o,c,p] * x[c, l shifted by p] * m_t[p,l]
// v5: (1) wave-uniform exact skip of all-zero (p,t,pixelgroup) fragments
//     (masks are {0,1}; if all 32 pixels of a fragment have bit 0 the MFMA
//     contributes exactly 0 -> skip is bit-exact);
//     (2) 128-px blocks, grid 1024 (~4 blocks/CU) so staging of one block
//     overlaps MFMA of another.

#define IN_C 32
#define OUT_C 64
#define IMG 256
#define HW 130          // halo width: 128 + 2

typedef __bf16 bf16x8 __attribute__((ext_vector_type(8)));
typedef float f32x16 __attribute__((ext_vector_type(16)));
union B128 { uint4 i4; bf16x8 v; };

// ---- prep: weights into A-fragment order (proven rounds 2-4) ---------------
// wA[q][ot][lane] (uint4 each), q = p*6 + t*2 + chalf.
// A[m = ot*32 + (lane&31)][k_in = (lane>>5)*8 + j], c = chalf*16 + k_in.
__global__ void build_wA(const float* __restrict__ w0,
                         const float* __restrict__ w1,
                         const float* __restrict__ w2,
                         __hip_bfloat16* __restrict__ wA) {
    int tid = blockIdx.x * 256 + threadIdx.x;      // q*128 + ot*64 + lane
    if (tid >= 54 * 128) return;
    int lane  = tid & 63;
    int ot    = (tid >> 6) & 1;
    int q     = tid >> 7;
    int p     = q / 6;
    int rm    = q - p * 6;
    int t     = rm >> 1;
    int chalf = rm & 1;
    int o     = ot * 32 + (lane & 31);
    int cbase = chalf * 16 + (lane >> 5) * 8;
    const float* w = (t == 0) ? w0 : (t == 1) ? w1 : w2;
    __hip_bfloat16* dst = wA + (size_t)tid * 8;
    #pragma unroll
    for (int j = 0; j < 8; ++j) {
        float v = w[(o * IN_C + cbase + j) * 9 + p];
        dst[j] = __float2bfloat16(v);
    }
}

// ---- main kernel -----------------------------------------------------------
// Block = 128 px of one row. 2n x 256row x 2colhalf = 1024 blocks.
// Wave w: ot = w&1 (32 outs), ph = w>>1 (64 px as 2 groups of 32).
__global__ __launch_bounds__(256, 3) void conv25d_mfma5(
    const float* __restrict__ x, const float* __restrict__ disp,
    const float* __restrict__ fx, const float* __restrict__ baseline,
    const uint4* __restrict__ wA, float* __restrict__ out) {

    // x halo strip as 4 k-slot planes: sx[(s*3 + r')*HW + cc2], 16 B entries.
    // plane s holds channels [s*8, s*8+8) of pixel (row+r'-1, colbase+cc2-1).
    __shared__ __align__(16) uint4 sx[12 * HW];    // 24960 B
    __shared__ float sdisp[3 * HW];                // 1560 B

    const int tid = threadIdx.x;
    const int bid = blockIdx.x;
    const int n       = bid >> 9;
    const int rem     = bid & 511;
    const int row     = rem >> 1;
    const int colbase = (rem & 1) << 7;            // 0 or 128

    // stage disp halo
    for (int idx = tid; idx < 3 * HW; idx += 256) {
        int r = idx / HW, cc2 = idx - r * HW;
        int gr = row + r - 1, gc = colbase + cc2 - 1;
        float v = 0.f;
        if (gr >= 0 && gr < IMG && gc >= 0 && gc < IMG)
            v = disp[(n * IMG + gr) * IMG + gc];
        sdisp[idx] = v;
    }
    // stage x halo strip: fp32 global -> bf16 LDS planes (conversion fused)
    for (int idx = tid; idx < 3 * HW; idx += 256) {
        int r = idx / HW, cc2 = idx - r * HW;
        int gr = row + r - 1, gc = colbase + cc2 - 1;
        bool ok = (gr >= 0) && (gr < IMG) && (gc >= 0) && (gc < IMG);
        unsigned w[16];
        #pragma unroll
        for (int j = 0; j < 16; ++j) w[j] = 0u;
        if (ok) {
            const float* src = x + ((size_t)(n * IN_C) * IMG + gr) * IMG + gc;
            #pragma unroll
            for (int j = 0; j < 16; ++j) {
                float a = src[(size_t)(2 * j) * (IMG * IMG)];
                float b = src[(size_t)(2 * j + 1) * (IMG * IMG)];
                __hip_bfloat162 h2 = __float22bfloat162_rn(make_float2(a, b));
                w[j] = *reinterpret_cast<unsigned*>(&h2);
            }
        }
        sx[(0 * 3 + r) * HW + cc2] = make_uint4(w[0],  w[1],  w[2],  w[3]);
        sx[(1 * 3 + r) * HW + cc2] = make_uint4(w[4],  w[5],  w[6],  w[7]);
        sx[(2 * 3 + r) * HW + cc2] = make_uint4(w[8],  w[9],  w[10], w[11]);
        sx[(3 * 3 + r) * HW + cc2] = make_uint4(w[12], w[13], w[14], w[15]);
    }
    __syncthreads();   // the only barrier

    const int lane = tid & 63;
    const int wv   = tid >> 6;
    const int ot   = wv & 1;          // out-half: outs [ot*32, ot*32+32)
    const int ph   = wv >> 1;         // pixel-half: cols [ph*64, ph*64+64)
    const int l31  = lane & 31;
    const int half = lane >> 5;
    const float fxv = fx[n];
    const float bfx = baseline[n] * fxv;

    // 27 mask bits per owned pixel (2 pixel-groups of 32)
    unsigned mbits[2];
    #pragma unroll
    for (int pg = 0; pg < 2; ++pg) {
        int l = ph * 64 + pg * 32 + l31;          // within-block col
        float dc = sdisp[HW + l + 1];
        float cd = bfx / fminf(fmaxf(dc, 0.01f), 256.f);
        float g  = 16.f * cd / fxv;
        float h  = g * 0.5f;
        unsigned bits = 0u;
        #pragma unroll
        for (int p = 0; p < 9; ++p) {
            int pi = p / 3, pj = p - pi * 3;
            float dval = sdisp[pi * HW + l + pj];
            bool validp = (dval != 0.f) && (dc != 0.f);
            float dmv   = validp ? dval : 0.f;
            float depth = bfx / fminf(fmaxf(dmv, 0.01f), 256.f);
            bool m0 = fabsf(depth - (cd + g)) <= h;
            bool m1 = (fabsf(depth - cd) <= h) || (!validp);
            bool m2 = fabsf(depth - (cd - g)) <= h;
            bits |= ((m0 ? 1u : 0u) << (3 * p))
                  | ((m1 ? 1u : 0u) << (3 * p + 1))
                  | ((m2 ? 1u : 0u) << (3 * p + 2));
        }
        mbits[pg] = bits;
    }

    // wave-uniform OR of mask bits per pixel-group -> SGPR (exact skip test)
    unsigned smu[2];
    #pragma unroll
    for (int pg = 0; pg < 2; ++pg) {
        unsigned b = mbits[pg];
        #pragma unroll
        for (int off = 32; off >= 1; off >>= 1)
            b |= (unsigned)__shfl_xor((int)b, off, 64);
        smu[pg] = __builtin_amdgcn_readfirstlane(b);
    }

    f32x16 acc[2];     // [pg]
    #pragma unroll
    for (int pg = 0; pg < 2; ++pg)
        #pragma unroll
        for (int r = 0; r < 16; ++r) acc[pg][r] = 0.f;

    const int cbase0 = ph * 64 + l31;

    #pragma unroll
    for (int p = 0; p < 9; ++p) {
        const int pi = p / 3, pj = p - pi * 3;

        // A-fragments for this tap: load unconditionally (L2-hot, lets the
        // compiler pipeline with vmcnt); skip only B-build + MFMA.
        B128 af[6];
        #pragma unroll
        for (int q = 0; q < 6; ++q)
            af[q].i4 = wA[(p * 6 + q) * 128 + ot * 64 + lane];

        // raw bf16 x fragments, read only if some t is active for this pg
        B128 xr[2][2];   // [pg][chalf]; plane s = chalf*2 + half
        #pragma unroll
        for (int pg = 0; pg < 2; ++pg) {
            if ((smu[pg] >> (3 * p)) & 7u) {
                int cc2 = cbase0 + pg * 32 + pj;
                #pragma unroll
                for (int ch = 0; ch < 2; ++ch)
                    xr[pg][ch].i4 = sx[((ch * 2 + half) * 3 + pi) * HW + cc2];
            }
        }

        #pragma unroll
        for (int t = 0; t < 3; ++t) {
            #pragma unroll
            for (int pg = 0; pg < 2; ++pg) {
                if ((smu[pg] >> (3 * p + t)) & 1u) {   // scalar branch
                    unsigned m = 0u - ((mbits[pg] >> (3 * p + t)) & 1u);
                    B128 b0, b1;
                    b0.i4 = make_uint4(xr[pg][0].i4.x & m, xr[pg][0].i4.y & m,
                                       xr[pg][0].i4.z & m, xr[pg][0].i4.w & m);
                    b1.i4 = make_uint4(xr[pg][1].i4.x & m, xr[pg][1].i4.y & m,
                                       xr[pg][1].i4.z & m, xr[pg][1].i4.w & m);
                    acc[pg] = __builtin_amdgcn_mfma_f32_32x32x16_bf16(
                                  af[t * 2 + 0].v, b0.v, acc[pg], 0, 0, 0);
                    acc[pg] = __builtin_amdgcn_mfma_f32_32x32x16_bf16(
                                  af[t * 2 + 1].v, b1.v, acc[pg], 0, 0, 0);
                }
            }
        }
    }

    // epilogue: D[o_local = (reg&3)+8*(reg>>2)+4*half][col = l31] (proven)
    float* ob = out + (size_t)(n * OUT_C) * (IMG * IMG)
              + (size_t)row * IMG + colbase + ph * 64 + l31;
    #pragma unroll
    for (int pg = 0; pg < 2; ++pg)
        #pragma unroll
        for (int reg = 0; reg < 16; ++reg) {
            int ol = (reg & 3) + 8 * (reg >> 2) + 4 * half + ot * 32;
            ob[(size_t)ol * (IMG * IMG) + pg * 32] = acc[pg][reg];
        }
}

extern "C" void kernel_launch(void* const* d_in, const int* in_sizes, int n_in,
                              void* d_out, int out_size, void* d_ws, size_t ws_size,
                              hipStream_t stream) {
    const float* x        = (const float*)d_in[0];
    const float* disp     = (const float*)d_in[1];
    const float* fx       = (const float*)d_in[2];
    const float* baseline = (const float*)d_in[3];
    const float* w0       = (const float*)d_in[4];
    const float* w1       = (const float*)d_in[5];
    const float* w2       = (const float*)d_in[6];
    float* out            = (float*)d_out;

    __hip_bfloat16* wA = (__hip_bfloat16*)d_ws;   // 54*128*16 = 110592 B

    build_wA<<<27, 256, 0, stream>>>(w0, w1, w2, wA);
    conv25d_mfma5<<<1024, 256, 0, stream>>>(x, disp, fx, baseline,
                                            (const uint4*)wA, out);
}

// Round 6
// 101.690 us; speedup vs baseline: 8.7866x; 1.0098x over previous
//
#include <hip/hip_runtime.h>
#include <hip/hip_bf16.h>

// Conv2.5D disparity-masked conv as implicit GEMM on bf16 MFMA, v6.
// D[o,l] = sum_{p,t,c} W_t[o,c,p] * x[c, l shifted by p] * m_t[p,l]
// v6: 64-px blocks, grid 2048, LDS 13.5 KB -> 8 blocks/CU (32 waves/CU, HW max)
// for staging/compute overlap. Wave = 32 outs x 32 px. Exact all-zero-fragment
// skip (bit-exact) retained from v5.

#define IN_C 32
#define OUT_C 64
#define IMG 256
#define HW 66           // halo width: 64 + 2

typedef __bf16 bf16x8 __attribute__((ext_vector_type(8)));
typedef float f32x16 __attribute__((ext_vector_type(16)));
union B128 { uint4 i4; bf16x8 v; };

// ---- prep: weights into A-fragment order (proven rounds 2-5) ---------------
// wA[q][ot][lane] (uint4 each), q = p*6 + t*2 + chalf.
// A[m = ot*32 + (lane&31)][k_in = (lane>>5)*8 + j], c = chalf*16 + k_in.
__global__ void build_wA(const float* __restrict__ w0,
                         const float* __restrict__ w1,
                         const float* __restrict__ w2,
                         __hip_bfloat16* __restrict__ wA) {
    int tid = blockIdx.x * 256 + threadIdx.x;      // q*128 + ot*64 + lane
    if (tid >= 54 * 128) return;
    int lane  = tid & 63;
    int ot    = (tid >> 6) & 1;
    int q     = tid >> 7;
    int p     = q / 6;
    int rm    = q - p * 6;
    int t     = rm >> 1;
    int chalf = rm & 1;
    int o     = ot * 32 + (lane & 31);
    int cbase = chalf * 16 + (lane >> 5) * 8;
    const float* w = (t == 0) ? w0 : (t == 1) ? w1 : w2;
    __hip_bfloat16* dst = wA + (size_t)tid * 8;
    #pragma unroll
    for (int j = 0; j < 8; ++j) {
        float v = w[(o * IN_C + cbase + j) * 9 + p];
        dst[j] = __float2bfloat16(v);
    }
}

// ---- main kernel -----------------------------------------------------------
// Block = 64 px of one row. 2n x 256row x 4colq = 2048 blocks (8/CU).
// Wave w: ot = w&1 (32 outs), ph = w>>1 (32 px).
__global__ __launch_bounds__(256, 8) void conv25d_mfma6(
    const float* __restrict__ x, const float* __restrict__ disp,
    const float* __restrict__ fx, const float* __restrict__ baseline,
    const uint4* __restrict__ wA, float* __restrict__ out) {

    // x halo strip as 4 k-slot planes: sx[(s*3 + r')*HW + cc2], 16 B entries.
    // plane s holds channels [s*8, s*8+8) of pixel (row+r'-1, colbase+cc2-1).
    __shared__ __align__(16) uint4 sx[12 * HW];    // 12672 B
    __shared__ float sdisp[3 * HW];                // 792 B

    const int tid = threadIdx.x;
    const int bid = blockIdx.x;
    const int n       = bid >> 10;
    const int rem     = bid & 1023;
    const int row     = rem >> 2;
    const int colbase = (rem & 3) << 6;            // 0/64/128/192

    // stage disp halo + x halo strip (fp32 -> bf16 planes), 198 idx < 256
    if (tid < 3 * HW) {
        int r = tid / HW, cc2 = tid - r * HW;
        int gr = row + r - 1, gc = colbase + cc2 - 1;
        bool ok = (gr >= 0) && (gr < IMG) && (gc >= 0) && (gc < IMG);
        float dv = 0.f;
        unsigned w[16];
        #pragma unroll
        for (int j = 0; j < 16; ++j) w[j] = 0u;
        if (ok) {
            dv = disp[(n * IMG + gr) * IMG + gc];
            const float* src = x + ((size_t)(n * IN_C) * IMG + gr) * IMG + gc;
            #pragma unroll
            for (int j = 0; j < 16; ++j) {
                float a = src[(size_t)(2 * j) * (IMG * IMG)];
                float b = src[(size_t)(2 * j + 1) * (IMG * IMG)];
                __hip_bfloat162 h2 = __float22bfloat162_rn(make_float2(a, b));
                w[j] = *reinterpret_cast<unsigned*>(&h2);
            }
        }
        sdisp[tid] = dv;
        sx[(0 * 3 + r) * HW + cc2] = make_uint4(w[0],  w[1],  w[2],  w[3]);
        sx[(1 * 3 + r) * HW + cc2] = make_uint4(w[4],  w[5],  w[6],  w[7]);
        sx[(2 * 3 + r) * HW + cc2] = make_uint4(w[8],  w[9],  w[10], w[11]);
        sx[(3 * 3 + r) * HW + cc2] = make_uint4(w[12], w[13], w[14], w[15]);
    }
    __syncthreads();   // the only barrier

    const int lane = tid & 63;
    const int wv   = tid >> 6;
    const int ot   = wv & 1;          // out-half: outs [ot*32, ot*32+32)
    const int ph   = wv >> 1;         // pixel-half: cols [ph*32, ph*32+32)
    const int l31  = lane & 31;
    const int half = lane >> 5;
    const float fxv = fx[n];
    const float bfx = baseline[n] * fxv;

    // 27 mask bits for this wave's 32 pixels
    const int l = ph * 32 + l31;      // within-block col
    unsigned mbits;
    {
        float dc = sdisp[HW + l + 1];
        float cd = bfx / fminf(fmaxf(dc, 0.01f), 256.f);
        float g  = 16.f * cd / fxv;
        float h  = g * 0.5f;
        unsigned bits = 0u;
        #pragma unroll
        for (int p = 0; p < 9; ++p) {
            int pi = p / 3, pj = p - pi * 3;
            float dval = sdisp[pi * HW + l + pj];
            bool validp = (dval != 0.f) && (dc != 0.f);
            float dmv   = validp ? dval : 0.f;
            float depth = bfx / fminf(fmaxf(dmv, 0.01f), 256.f);
            bool m0 = fabsf(depth - (cd + g)) <= h;
            bool m1 = (fabsf(depth - cd) <= h) || (!validp);
            bool m2 = fabsf(depth - (cd - g)) <= h;
            bits |= ((m0 ? 1u : 0u) << (3 * p))
                  | ((m1 ? 1u : 0u) << (3 * p + 1))
                  | ((m2 ? 1u : 0u) << (3 * p + 2));
        }
        mbits = bits;
    }

    // wave-uniform OR of mask bits -> SGPR (exact skip test)
    unsigned smu;
    {
        unsigned b = mbits;
        #pragma unroll
        for (int off = 32; off >= 1; off >>= 1)
            b |= (unsigned)__shfl_xor((int)b, off, 64);
        smu = __builtin_amdgcn_readfirstlane(b);
    }

    f32x16 acc;
    #pragma unroll
    for (int r = 0; r < 16; ++r) acc[r] = 0.f;

    #pragma unroll
    for (int p = 0; p < 9; ++p) {
        const int pi = p / 3, pj = p - pi * 3;
        if (!((smu >> (3 * p)) & 7u)) continue;    // whole tap dead (scalar)

        // raw bf16 x fragments (lane-contiguous b128 LDS reads)
        B128 xr[2];   // [chalf]; plane s = chalf*2 + half
        const int cc2 = l + pj;
        #pragma unroll
        for (int ch = 0; ch < 2; ++ch)
            xr[ch].i4 = sx[((ch * 2 + half) * 3 + pi) * HW + cc2];

        #pragma unroll
        for (int t = 0; t < 3; ++t) {
            if ((smu >> (3 * p + t)) & 1u) {       // scalar branch
                unsigned m = 0u - ((mbits >> (3 * p + t)) & 1u);
                B128 a0, a1, b0, b1;
                a0.i4 = wA[(p * 6 + t * 2 + 0) * 128 + ot * 64 + lane];
                a1.i4 = wA[(p * 6 + t * 2 + 1) * 128 + ot * 64 + lane];
                b0.i4 = make_uint4(xr[0].i4.x & m, xr[0].i4.y & m,
                                   xr[0].i4.z & m, xr[0].i4.w & m);
                b1.i4 = make_uint4(xr[1].i4.x & m, xr[1].i4.y & m,
                                   xr[1].i4.z & m, xr[1].i4.w & m);
                acc = __builtin_amdgcn_mfma_f32_32x32x16_bf16(a0.v, b0.v, acc, 0, 0, 0);
                acc = __builtin_amdgcn_mfma_f32_32x32x16_bf16(a1.v, b1.v, acc, 0, 0, 0);
            }
        }
    }

    // epilogue: D[o_local = (reg&3)+8*(reg>>2)+4*half][col = l31] (proven)
    float* ob = out + (size_t)(n * OUT_C) * (IMG * IMG)
              + (size_t)row * IMG + colbase + ph * 32 + l31;
    #pragma unroll
    for (int reg = 0; reg < 16; ++reg) {
        int ol = (reg & 3) + 8 * (reg >> 2) + 4 * half + ot * 32;
        ob[(size_t)ol * (IMG * IMG)] = acc[reg];
    }
}

extern "C" void kernel_launch(void* const* d_in, const int* in_sizes, int n_in,
                              void* d_out, int out_size, void* d_ws, size_t ws_size,
                              hipStream_t stream) {
    const float* x        = (const float*)d_in[0];
    const float* disp     = (const float*)d_in[1];
    const float* fx       = (const float*)d_in[2];
    const float* baseline = (const float*)d_in[3];
    const float* w0       = (const float*)d_in[4];
    const float* w1       = (const float*)d_in[5];
    const float* w2       = (const float*)d_in[6];
    float* out            = (float*)d_out;

    __hip_bfloat16* wA = (__hip_bfloat16*)d_ws;   // 54*128*16 = 110592 B

    build_wA<<<27, 256, 0, stream>>>(w0, w1, w2, wA);
    conv25d_mfma6<<<2048, 256, 0, stream>>>(x, disp, fx, baseline,
                                            (const uint4*)wA, out);
}